// Round 7
// baseline (338.709 us; speedup 1.0000x reference)
//
#include <hip/hip_runtime.h>
#include <math.h>

#define WIN 11
#define PAD 5
#define TW 64              // tile width = wave width

typedef float v2f __attribute__((ext_vector_type(2)));

struct GW { float g[WIN]; };

// ---------------------------------------------------------------------------
// Wave-autonomous SSIM tile, DOUBLE-ROW STATIC-RING edition.
// R0-R6 meta-result: dur ~= VALU-work / ~0.45 across every structural variant
// (latency tricks null; VALUBusy pinned ~45-50% by issue/DS contention that
// scales with the instruction stream). So: cut instructions. One loop step
// processes TWO image rows (2d, 2d+1):
//   - LDS float4 (p0,q0,p1,q1): 11 ds_read_b128 + 2 writes per 2 rows
//     (halves DS instruction count vs per-row float2)
//   - H-conv of both rows off one read: 6 pk-ops/tap per 2 rows
//   - V-conv PACKED accumulators vM[s]=(Mp,Mq), vS[s]=(Sp,Sq): 44 pk_fma
//     per 2 rows (vs 88 scalar). This is safe where R1 spilled: R1 SHIFTED
//     22 loop-carried pairs every row; these are a STATIC 12-slot ring —
//     compile-time indices, zero copies. Tripwire: WRITE_SIZE ~24.8MB.
//   - 12-slot ring, phase = d mod 6: slot s holds output o == s (mod 12);
//     at step d slots (2u+2)%12,(2u+3)%12 complete outputs 2d-10, 2d-9.
//     Tap weights per (s,u) compile-time: w0 = (2u-s) mod 12 (row 2d, if
//     <=10), w1 = (w0+1) mod 12 (row 2d+1, if <=10).
//   - 21 double-steps cover rows 0..41 EXACTLY (3x6 unrolled + 3-step tail,
//     u literal in both) - zero waste rows.
// Retained: branchless loads (R5, uniform vmcnt), depth-1-step prefetch
// (= 2 rows ahead), sched_barrier(0) at step end (R8 unroll-hoist trap),
// wave_barrier pair around the LDS phase. Numerics: identical op order to
// R4-R6 (absmax was exactly 0) - pk elementwise == the scalar pair.
// EMIT: L0 pools rows (2d-1, 2d) into L1 at steps with 6 <= 2d <= 36.
// ---------------------------------------------------------------------------
template<bool EMIT>
__device__ __forceinline__ float ssim_wave_tile(
    const float* __restrict__ p1, const float* __restrict__ p2,
    int W, int X0, int Y0, const GW& gw, float4* __restrict__ rb,
    float* __restrict__ o1a, float* __restrict__ o1b, int Wout)
{
    const int TH = 32;
    const int lane = threadIdx.x & 63;
    const int gx = X0 + lane;
    const bool cval = gx < W;                              // false only for L4 lanes 32+
    const int hx   = (lane < 5) ? (X0 - 5 + lane) : (X0 + 59 + lane);
    const bool hval = (lane < 10) && ((unsigned)hx < (unsigned)W);
    const int hpos = (lane < 5) ? lane : (64 + lane);      // 0..4 | 69..73
    const int cpos = 5 + lane;
    const int gxc = cval ? gx : 0;                         // clamped main col
    const int hxc = hval ? hx : gxc;                       // masked halo -> own col (L1 hit)
    const int wpos = (lane < 10) ? hpos : cpos;            // branchless LDS halo write

    v2f vM[12], vS[12];                                    // packed (Mp,Mq)/(Sp,Sq)
#pragma unroll
    for (int k = 0; k < 12; ++k) { vM[k] = (v2f){0.f, 0.f}; vS[k] = (v2f){0.f, 0.f}; }

    float part = 0.f;
    float pprev = 0.f, qprev = 0.f;

    // BRANCHLESS per-row load: 4 unconditional global_load_dword, results
    // zero-selected. Statically uniform load count -> counted vmcnt.
    auto LOAD = [&](int t, float& oa, float& ob, float& oah, float& obh) {
        int y = Y0 - PAD + t;
        bool yin = (unsigned)y < (unsigned)W;
        const float* r1 = p1 + (size_t)(yin ? y : 0) * W;
        const float* r2 = p2 + (size_t)(yin ? y : 0) * W;
        float va = r1[gxc], vb = r2[gxc];
        float wa = r1[hxc], wb = r2[hxc];
        bool cv = yin && cval;
        bool hv = yin && hval;
        oa  = cv ? va : 0.f;
        ob  = cv ? vb : 0.f;
        oah = hv ? wa : 0.f;
        obh = hv ? wb : 0.f;
    };

    auto EMIT1 = [&](v2f M, v2f S, int o) {
        if ((unsigned)o < (unsigned)TH) {
            bool yok = (unsigned)(Y0 + o) < (unsigned)W;   // false only for L4 tail
            float Mp = M.x, Mq = M.y, Sp_ = S.x, Sq_ = S.y;
            const float C1v = 1e-4f, C2v = 9e-4f;
            float A = Mp * Mp, B = Mq * Mq;
            float ABp = A + B, ABm = A - B;
            float SSp = Sp_ + Sq_, SSm = Sp_ - Sq_;
            float n1 = fmaf(0.5f, ABm, C1v);         // 2*m12 + C1
            float n2 = fmaf(0.5f, SSm - ABm, C2v);   // 2*s12 + C2
            float e1 = fmaf(0.5f, ABp, C1v);         // m1^2+m2^2 + C1
            float e2 = fmaf(0.5f, SSp - ABp, C2v);   // s1+s2 + C2
            float val = (n1 * n2) * __builtin_amdgcn_rcpf(e1 * e2);
            part += (cval && yok) ? val : 0.f;
        }
    };

    // current double-row (2d, 2d+1) and next (2d+2, 2d+3)
    float c0a, c0b, c0ah, c0bh, c1a, c1b, c1ah, c1bh;
    float n0a, n0b, n0ah, n0bh, n1a, n1b, n1ah, n1bh;
    LOAD(0, c0a, c0b, c0ah, c0bh);
    LOAD(1, c1a, c1b, c1ah, c1bh);

#define SSIM_STEP(D_, U_) do {                                                \
    const int d_ = (D_);                                                      \
    /* 1) issue next double-row loads (consumed next step) */                 \
    LOAD(2*d_ + 2, n0a, n0b, n0ah, n0bh);                                     \
    LOAD(2*d_ + 3, n1a, n1b, n1ah, n1bh);                                     \
    /* 2) LDS write rows (2d, 2d+1) packed as float4 */                       \
    float p0 = c0a + c0b, q0 = c0a - c0b;                                     \
    float p1r = c1a + c1b, q1r = c1a - c1b;                                   \
    float ph0 = c0ah + c0bh, qh0 = c0ah - c0bh;                               \
    float ph1 = c1ah + c1bh, qh1 = c1ah - c1bh;                               \
    rb[cpos] = make_float4(p0, q0, p1r, q1r);                                 \
    rb[wpos] = (lane < 10) ? make_float4(ph0, qh0, ph1, qh1)                  \
                           : make_float4(p0, q0, p1r, q1r);                   \
    __builtin_amdgcn_wave_barrier();   /* writes -> reads (cross-lane RAW) */ \
    /* 3) H-conv of both rows from one b128 read per tap */                   \
    v2f hM0 = {0.f,0.f}, hS0 = {0.f,0.f}, hM1 = {0.f,0.f}, hS1 = {0.f,0.f};  \
    _Pragma("unroll")                                                         \
    for (int j = 0; j < WIN; ++j) {                                           \
        float4 vv = rb[lane + j];                                             \
        v2f v0 = { vv.x, vv.y }, v1 = { vv.z, vv.w };                         \
        v2f g2 = { gw.g[j], gw.g[j] };                                        \
        hM0 = __builtin_elementwise_fma(g2, v0, hM0);                         \
        hS0 = __builtin_elementwise_fma(g2, v0 * v0, hS0);                    \
        hM1 = __builtin_elementwise_fma(g2, v1, hM1);                         \
        hS1 = __builtin_elementwise_fma(g2, v1 * v1, hS1);                    \
    }                                                                         \
    __builtin_amdgcn_wave_barrier();   /* reads -> next step's writes (WAR) */\
    /* 4) V-conv static ring, packed accumulators */                          \
    _Pragma("unroll")                                                         \
    for (int s = 0; s < 12; ++s) {                                            \
        const int w0v = ((2*(U_) - s) % 12 + 12) % 12;                        \
        if (w0v <= 10) {                                                      \
            v2f g2 = { gw.g[w0v], gw.g[w0v] };                                \
            vM[s] = __builtin_elementwise_fma(g2, hM0, vM[s]);                \
            vS[s] = __builtin_elementwise_fma(g2, hS0, vS[s]);                \
        }                                                                     \
        const int w1v = (w0v + 1) % 12;                                       \
        if (w1v <= 10) {                                                      \
            v2f g2 = { gw.g[w1v], gw.g[w1v] };                                \
            vM[s] = __builtin_elementwise_fma(g2, hM1, vM[s]);                \
            vS[s] = __builtin_elementwise_fma(g2, hS1, vS[s]);                \
        }                                                                     \
    }                                                                         \
    /* 5) emit the two completed outputs (o=2d-10, 2d-9), zero their slots */ \
    {                                                                         \
        const int s0_ = (2*(U_) + 2) % 12;                                    \
        const int s1_ = (2*(U_) + 3) % 12;                                    \
        EMIT1(vM[s0_], vS[s0_], 2*d_ - 10);                                   \
        EMIT1(vM[s1_], vS[s1_], 2*d_ - 9);                                    \
        vM[s0_] = (v2f){0.f,0.f}; vS[s0_] = (v2f){0.f,0.f};                   \
        vM[s1_] = (v2f){0.f,0.f}; vS[s1_] = (v2f){0.f,0.f};                   \
    }                                                                         \
    /* 6) L0 pooling of image rows (2d-1, 2d) -> L1 */                        \
    if (EMIT) {                                                               \
        int r_ = 2*d_;                                                        \
        if (r_ >= 6 && r_ <= TH + 4) {                                        \
            float sp_ = p0 + pprev, sq_ = q0 + qprev;                         \
            float sp2 = sp_ + __shfl_down(sp_, 1, 64);                        \
            float sq2 = sq_ + __shfl_down(sq_, 1, 64);                        \
            if ((lane & 1) == 0) {                                            \
                float P = sp2 * 0.25f, Q = sq2 * 0.25f;                       \
                int yo = d_ - 3;                                              \
                size_t oo = (size_t)((Y0 >> 1) + yo) * Wout                   \
                          + ((X0 >> 1) + (lane >> 1));                        \
                o1a[oo] = (P + Q) * 0.5f;                                     \
                o1b[oo] = (P - Q) * 0.5f;                                     \
            }                                                                 \
        }                                                                     \
        pprev = p1r; qprev = q1r;                                             \
    }                                                                         \
    /* 7) rotate prefetch regs */                                             \
    c0a = n0a; c0b = n0b; c0ah = n0ah; c0bh = n0bh;                           \
    c1a = n1a; c1b = n1b; c1ah = n1ah; c1bh = n1bh;                           \
    /* pin step boundary: no cross-step motion (R8 unroll-hoist trap) */      \
    __builtin_amdgcn_sched_barrier(0);                                        \
} while (0)

    // 21 double-steps (rows 0..41): 3 unrolled blocks of 6 + 3-step tail.
    // Phase u = d mod 6 is a LITERAL at every expansion (weights fold).
#pragma unroll 1
    for (int blk = 0; blk < 3; ++blk) {
        const int db = blk * 6;
        SSIM_STEP(db + 0, 0);
        SSIM_STEP(db + 1, 1);
        SSIM_STEP(db + 2, 2);
        SSIM_STEP(db + 3, 3);
        SSIM_STEP(db + 4, 4);
        SSIM_STEP(db + 5, 5);
    }
    SSIM_STEP(18, 0);
    SSIM_STEP(19, 1);
    SSIM_STEP(20, 2);

#undef SSIM_STEP

    return part;
}

// ---- L0: 8x16 tiles (64x32) x 48 images = 6144 waves (1536 blocks); emits L1 ----
__global__ __launch_bounds__(256, 4) void ssim_l0_kernel(
    const float* __restrict__ i1, const float* __restrict__ i2,
    float* __restrict__ a1, float* __restrict__ b1,
    double* __restrict__ acc, GW gw)
{
    __shared__ float4 rbs[4][80];
    const int wid = threadIdx.x >> 6;
    const int w = blockIdx.x * 4 + wid;
    const int img = w >> 7;                 // 128 tiles per image
    const int tt = w & 127;
    const int tx = tt & 7, ty = tt >> 3;    // 8 cols x 16 rows
    const size_t off  = (size_t)img * 512 * 512;
    const size_t ooff = (size_t)img * 256 * 256;

    float part = ssim_wave_tile<true>(i1 + off, i2 + off, 512, tx * 64, ty * 32,
                                      gw, rbs[wid], a1 + ooff, b1 + ooff, 256);
#pragma unroll
    for (int o = 32; o > 0; o >>= 1) part += __shfl_down(part, o, 64);
    if ((threadIdx.x & 63) == 0) atomicAdd(acc, (double)part);
}

// ---- L1..L4, all 64x32 tiles: 32+8+2+1 = 43 tiles/image = 2064 waves (516 blocks) ----
__global__ __launch_bounds__(256, 4) void ssim_rest_kernel(
    const float* __restrict__ a1, const float* __restrict__ b1,
    const float* __restrict__ a2, const float* __restrict__ b2,
    const float* __restrict__ a3, const float* __restrict__ b3,
    const float* __restrict__ a4, const float* __restrict__ b4,
    double* __restrict__ acc, GW gw)
{
    __shared__ float4 rbs[4][80];
    const int wid = threadIdx.x >> 6;
    const int w = blockIdx.x * 4 + wid;
    const int img = w / 43;
    const int r = w - img * 43;
    int lvl, tx, ty;
    if (r < 32)      { lvl = 1; tx = r & 3;  ty = r >> 2; }                // 4x8
    else if (r < 40) { lvl = 2; int s = r - 32; tx = s & 1; ty = s >> 1; } // 2x4
    else if (r < 42) { lvl = 3; tx = 0; ty = r - 40; }                     // 1x2
    else             { lvl = 4; tx = 0; ty = 0; }                          // 1x1
    const int W = 512 >> lvl;
    const float* p1; const float* p2;
    switch (lvl) {
      case 1:  p1 = a1; p2 = b1; break;
      case 2:  p1 = a2; p2 = b2; break;
      case 3:  p1 = a3; p2 = b3; break;
      default: p1 = a4; p2 = b4; break;
    }
    const size_t off = (size_t)img * W * W;

    float part = ssim_wave_tile<false>(p1 + off, p2 + off, W, tx * 64, ty * 32,
                                       gw, rbs[wid], nullptr, nullptr, 0);
#pragma unroll
    for (int o = 32; o > 0; o >>= 1) part += __shfl_down(part, o, 64);
    if ((threadIdx.x & 63) == 0) atomicAdd(acc + lvl, (double)part);
}

// ---- pool L1 -> L2/L3/L4. Grid (16, 96). ----
__global__ __launch_bounds__(256) void pool_rest_kernel(
    const float* __restrict__ a1, const float* __restrict__ b1,
    float* __restrict__ a2, float* __restrict__ b2,
    float* __restrict__ a3, float* __restrict__ b3,
    float* __restrict__ a4, float* __restrict__ b4)
{
    __shared__ float l2[32][33];
    __shared__ float l3[16][17];
    const int tid = threadIdx.x;
    const int im = blockIdx.y;
    const int tb = blockIdx.x;
    const int tx = tb & 3, ty = tb >> 2;
    const bool second = im >= 48;
    const int ii = second ? im - 48 : im;
    const float* src = (second ? b1 : a1) + (size_t)ii * 256 * 256;
    float* o2 = (second ? b2 : a2) + (size_t)ii * 128 * 128;
    float* o3 = (second ? b3 : a3) + (size_t)ii * 64 * 64;
    float* o4 = (second ? b4 : a4) + (size_t)ii * 32 * 32;
    const int X0 = tx * 64, Y0 = ty * 64;

#pragma unroll
    for (int k = 0; k < 2; ++k) {
        int idx = tid + k * 256;
        int xp = idx & 15;
        int yo = idx >> 4;
        const float* rp = src + (size_t)(Y0 + 2 * yo) * 256 + (X0 + 4 * xp);
        float4 r0 = *(const float4*)rp;
        float4 r1 = *(const float4*)(rp + 256);
        float v0 = (r0.x + r0.y + r1.x + r1.y) * 0.25f;
        float v1 = (r0.z + r0.w + r1.z + r1.w) * 0.25f;
        l2[yo][2 * xp]     = v0;
        l2[yo][2 * xp + 1] = v1;
        float2* op = (float2*)(o2 + (size_t)((Y0 >> 1) + yo) * 128 + ((X0 >> 1) + 2 * xp));
        *op = make_float2(v0, v1);
    }
    __syncthreads();
    {
        int xo = tid & 15, yo = tid >> 4;
        if (yo < 16) {
            float v = (l2[2*yo][2*xo] + l2[2*yo][2*xo+1] +
                       l2[2*yo+1][2*xo] + l2[2*yo+1][2*xo+1]) * 0.25f;
            l3[yo][xo] = v;
            o3[(size_t)((Y0 >> 2) + yo) * 64 + ((X0 >> 2) + xo)] = v;
        }
    }
    __syncthreads();
    if (tid < 64) {
        int xo = tid & 7, yo = tid >> 3;
        float v = (l3[2*yo][2*xo] + l3[2*yo][2*xo+1] +
                   l3[2*yo+1][2*xo] + l3[2*yo+1][2*xo+1]) * 0.25f;
        o4[(size_t)((Y0 >> 3) + yo) * 32 + ((X0 >> 3) + xo)] = v;
    }
}

__global__ void final_kernel(const double* __restrict__ acc, float* __restrict__ out)
{
    double loss = 0.0;
#pragma unroll
    for (int l = 0; l < 5; ++l) {
        double cnt = 48.0 * (double)(512 >> l) * (double)(512 >> l);
        loss += 1.0 - acc[l] / cnt;
    }
    out[0] = (float)loss;
}

extern "C" void kernel_launch(void* const* d_in, const int* in_sizes, int n_in,
                              void* d_out, int out_size, void* d_ws, size_t ws_size,
                              hipStream_t stream)
{
    const float* img1 = (const float*)d_in[0];
    const float* img2 = (const float*)d_in[1];
    float* out = (float*)d_out;

    // 1D gaussian (sigma=1.5, k=11), matches reference construction
    GW gw;
    double gs[WIN], sum = 0.0;
    for (int i = 0; i < WIN; ++i) {
        double ax = (double)i - 5.0;
        gs[i] = exp(-(ax * ax) / 4.5);
        sum += gs[i];
    }
    for (int i = 0; i < WIN; ++i) gw.g[i] = (float)(gs[i] / sum);

    // workspace: 64B header (5 double acc), then pyramid
    double* acc = (double*)d_ws;
    float* base = (float*)((char*)d_ws + 64);
    const size_t n1 = 48ull * 256 * 256;
    const size_t n2 = 48ull * 128 * 128;
    const size_t n3 = 48ull * 64 * 64;
    const size_t n4 = 48ull * 32 * 32;
    float* a1 = base;      float* b1 = a1 + n1;
    float* a2 = b1 + n1;   float* b2 = a2 + n2;
    float* a3 = b2 + n2;   float* b3 = a3 + n3;
    float* a4 = b3 + n3;   float* b4 = a4 + n4;

    hipMemsetAsync(acc, 0, 5 * sizeof(double), stream);

    hipLaunchKernelGGL(ssim_l0_kernel, dim3(1536), dim3(256), 0, stream,
                       img1, img2, a1, b1, acc, gw);

    hipLaunchKernelGGL(pool_rest_kernel, dim3(16, 96), dim3(256), 0, stream,
                       a1, b1, a2, b2, a3, b3, a4, b4);

    hipLaunchKernelGGL(ssim_rest_kernel, dim3(516), dim3(256), 0, stream,
                       a1, b1, a2, b2, a3, b3, a4, b4, acc, gw);

    hipLaunchKernelGGL(final_kernel, dim3(1), dim3(1), 0, stream, acc, out);
}